// Round 11
// baseline (360.085 us; speedup 1.0000x reference)
//
#include <hip/hip_runtime.h>

#define NB 256
#define NT 1024
#define NUNF 6
#define TB 64
#define NTILE (NT / TB)
#define CHK 6
#define L2E 1.44269504088896340736f

typedef const float* fp;

extern "C" __device__ float __ocml_exp2_f32(float);
__device__ __forceinline__ float frcp(float x) { return __builtin_amdgcn_rcpf(x); }
__device__ __forceinline__ float ex2(float x) { return __ocml_exp2_f32(x); }
__device__ __forceinline__ float sgm(float a, float b, float v) { return frcp(1.f + ex2(fmaf(a, v, b))); }

struct Tables {
    int ngroups, npos, nchunks, pad0;
    int grp_start[21];
    int ord[20];
    int pos[20];
    int aff[20];
    int ch_ps[20], ch_pe[20], ch_gs[20], ch_ge[20];
    int ncp[20], nip[20], ngp[20];
    float cmt[20], cn0[20], cd0[20];
    float icmt[12];
    int   cp_pre[20][8];
    float cp_a[20][8], cp_b[20][8], cp_w[20][8], cp_e[20][8];
    int   ip_i[20][12];
    float ip_a[20][12], ip_b[20][12], ip_w[20][12], ip_e[20][12];
    int   gp_pre[20][6];
    float gp_a[20][6], gp_b[20][6], gp_w[20][6], gp_e[20][6];
};

struct DenseTab {
    int cnt[12];
    float in0[12], id0[12];
    int   pre[12][32];
    float a[12][32], b[12][32], w[12][32], e[12][32];
};

#define WS_DTAB 16384

// ---------------- K0: wiring analysis, lane-parallel in LDS (unchanged) ----------------
__global__ void build_tables(fp wsyn, fp mu, fp sigma, fp erev, const int* spm,
                             fp sw, fp smu, fp ssg, fp serev, const int* smask,
                             fp cm, fp gleak, fp vleak, Tables* T, DenseTab* D) {
    __shared__ int   spmL[1024], smkL[1024];
    __shared__ float wL[1024], muL[1024], sgL[1024], evL[1024];
    __shared__ float swL[1024], smuL[1024], ssgL[1024], sevL[1024];
    __shared__ float cmL[32], glL[32], vlL[32];
    __shared__ int premaskL[20], ancL[20], rootL[20], depUL[20], keyL[20], posL[20], ordL[20];
    __shared__ int ngpL[20];
    __shared__ int neededS;
    int tid = threadIdx.x;
    for (int k = tid; k < 1024; k += 64) {
        spmL[k] = spm[k]; wL[k] = wsyn[k]; muL[k] = mu[k]; sgL[k] = sigma[k]; evL[k] = erev[k];
        smkL[k] = smask[k]; swL[k] = sw[k]; smuL[k] = smu[k]; ssgL[k] = ssg[k]; sevL[k] = serev[k];
    }
    if (tid < 32) { cmL[tid] = cm[tid]; glL[tid] = gleak[tid]; vlL[tid] = vleak[tid]; }
    __syncthreads();
    if (tid < 20) {
        int pm = 0;
        for (int i = 0; i < 20; ++i) if (spmL[i * 32 + tid]) pm |= 1 << i;
        premaskL[tid] = pm;
        ancL[tid] = pm;
    }
    __syncthreads();
    for (int it = 0; it < 20; ++it) {
        int a = 0;
        if (tid < 20) {
            a = ancL[tid];
            int pm = premaskL[tid];
            for (int i = 0; i < 20; ++i) if ((pm >> i) & 1) a |= ancL[i];
        }
        __syncthreads();
        if (tid < 20) ancL[tid] = a;
        __syncthreads();
    }
    if (tid == 0) neededS = ancL[0] | 1;
    __syncthreads();
    int needed = neededS;
    if (tid < 20) {
        int r = tid;
        if ((needed >> tid) & 1) {
            int aj = ancL[tid];
            for (int i = 0; i < 20; ++i)
                if (i < r && ((needed >> i) & 1) && ((aj >> i) & 1) && ((ancL[i] >> tid) & 1)) r = i;
        }
        rootL[tid] = r;
        depUL[tid] = 0;
    }
    __syncthreads();
    for (int it = 0; it < 21; ++it) {
        int d = 0;
        if (tid < 20 && ((needed >> tid) & 1)) {
            int pm = premaskL[tid], myr = rootL[tid];
            for (int i = 0; i < 20; ++i)
                if (((pm >> i) & 1) && rootL[i] != myr) d = max(d, depUL[i] + 1);
        }
        __syncthreads();
        if (tid < 20 && d > depUL[tid]) depUL[tid] = d;
        __syncthreads();
    }
    if (tid < 20) {
        int key = 0x7FFFFFFF;
        if ((needed >> tid) & 1) {
            int myr = rootL[tid], dg = 0;
            for (int i = 0; i < 20; ++i)
                if (((needed >> i) & 1) && rootL[i] == myr) dg = max(dg, depUL[i]);
            key = dg * 32 + myr;
        }
        keyL[tid] = key;
    }
    __syncthreads();
    if (tid < 20) {
        int mykey = keyL[tid];
        int p = 0;
        for (int k = 0; k < 20; ++k)
            if (keyL[k] < mykey || (keyL[k] == mykey && k < tid)) ++p;
        posL[tid] = p;
        if (p < 20) ordL[p] = tid;
    }
    __syncthreads();
    if (tid < 20) {
        int j = tid, cc = 0, ci = 0, cg = 0;
        T->cmt[j] = cmL[j] * (float)NUNF;
        T->cn0[j] = glL[j] * vlL[j];
        T->cd0[j] = cmL[j] * (float)NUNF + glL[j] + 1e-8f;
        if ((needed >> j) & 1) {
            int myr = rootL[j];
            int mystart = posL[myr];
            for (int i = 0; i < 32; ++i) {
                int p = i * 32 + j;
                if (!spmL[p]) continue;
                float sg = sgL[p];
                float a = -sg * L2E, b = sg * muL[p] * L2E;
                float w = wL[p], e = w * evL[p];
                if (i >= 20) {
                    T->ip_i[j][ci] = i - 20;
                    T->ip_a[j][ci] = a; T->ip_b[j][ci] = b; T->ip_w[j][ci] = w; T->ip_e[j][ci] = e;
                    ++ci;
                } else if (rootL[i] == myr) {
                    T->gp_pre[j][cg] = posL[i] - mystart;
                    T->gp_a[j][cg] = a; T->gp_b[j][cg] = b; T->gp_w[j][cg] = w; T->gp_e[j][cg] = e;
                    ++cg;
                } else {
                    T->cp_pre[j][cc] = posL[i];
                    T->cp_a[j][cc] = a; T->cp_b[j][cc] = b; T->cp_w[j][cc] = w; T->cp_e[j][cc] = e;
                    ++cc;
                }
            }
        }
        T->ncp[j] = cc; T->nip[j] = ci; T->ngp[j] = cg;
        ngpL[j] = cg;
    }
    if (tid < 12) {
        T->icmt[tid] = cmL[20 + tid] * (float)NUNF;
        int unit = 20 + tid, cnt = 0;
        for (int s = 0; s < 32; ++s) {
            int p = s * 32 + unit;
            if (!smkL[p]) continue;
            float sg = ssgL[p];
            D->pre[tid][cnt] = s;
            D->a[tid][cnt] = -sg * L2E;
            D->b[tid][cnt] = sg * smuL[p] * L2E;
            D->w[tid][cnt] = swL[p];
            D->e[tid][cnt] = swL[p] * sevL[p];
            ++cnt;
        }
        for (int c = cnt; c < 32; ++c) {
            D->pre[tid][c] = 0; D->a[tid][c] = 0.f; D->b[tid][c] = 0.f;
            D->w[tid][c] = 0.f; D->e[tid][c] = 0.f;
        }
        D->cnt[tid] = cnt;
        D->in0[tid] = glL[unit] * vlL[unit];
        D->id0[tid] = cmL[unit] * (float)NUNF + glL[unit] + 1e-8f;
    }
    __syncthreads();
    if (tid == 0) {
        int npos = __popc(needed & 0xFFFFF);
        T->npos = npos;
        int ng = 0, prevkey = -1;
        for (int p = 0; p < npos; ++p) {
            int u = ordL[p];
            if (keyL[u] != prevkey) { T->grp_start[ng] = p; ++ng; prevkey = keyL[u]; }
        }
        T->ngroups = ng;
        for (int g = ng; g <= 20; ++g) T->grp_start[g] = npos;
        for (int p = 0; p < 20; ++p) T->ord[p] = (p < npos) ? ordL[p] : 0;
        for (int j = 0; j < 20; ++j) T->pos[j] = posL[j];
        for (int g = 0; g < ng; ++g) {
            int gs = T->grp_start[g], ge = T->grp_start[g + 1], gsz = ge - gs;
            for (int p = gs; p < ge; ++p)
                T->aff[p] = (gsz == 1 && ngpL[ordL[p]] == 0) ? 1 : 0;
        }
        for (int p = npos; p < 20; ++p) T->aff[p] = 0;
        int nchunks = 0, g = 0;
        while (g < ng) {
            int lvl = keyL[ordL[T->grp_start[g]]] / 32;
            int ge = g;
            while (ge < ng && keyL[ordL[T->grp_start[ge]]] / 32 == lvl) ++ge;
            int cs = g;
            while (cs < ge) {
                int ce = cs, acc = 0;
                while (ce < ge) {
                    int gsz = T->grp_start[ce + 1] - T->grp_start[ce];
                    if (acc + gsz > CHK && ce > cs) break;
                    acc += gsz; ++ce;
                    if (acc >= CHK) break;
                }
                T->ch_gs[nchunks] = cs; T->ch_ge[nchunks] = ce;
                T->ch_ps[nchunks] = T->grp_start[cs]; T->ch_pe[nchunks] = T->grp_start[ce];
                ++nchunks;
                cs = ce;
            }
            g = ge;
        }
        T->nchunks = nchunks;
    }
}

// ---------------- K1: fused dense+solve. 1 block per batch, 512 threads. ----------------
// Waves 0-3: level-parallel LTC solver. Waves 4-7: dense stack + sensory gates for the
// NEXT tile into a 2-slot LDS ring. Barrier counts uniform across both halves.
__global__ __launch_bounds__(512) void fused(
    fp x, fp d1w, fp d1b, fp d2w, fp d2b, fp iw, fp ib,
    const DenseTab* __restrict__ Dg, const Tables* __restrict__ Tg,
    fp ow, fp ob, float* out) {
    __shared__ float W2s[4096];
    __shared__ float b2q[32], iwq[32], ibq[32];
    __shared__ int   preT[32 * 13];
    __shared__ float aT[32 * 13], bT[32 * 13], wT[32 * 13], eT[32 * 13];
    __shared__ int   cntL[12];
    __shared__ float in0L[12], id0L[12];
    __shared__ float hbuf[4][8][132];
    __shared__ float ibuf[4][8][33];
    __shared__ float2 ring[2][TB][13];         // [slot][tt][inter(12, pad 13)]
    __shared__ Tables TL;
    __shared__ float viter[TB * 13];
    __shared__ float vtraj[20 * TB * 6];       // stride 6 (2-way bank alias, free)
    __shared__ float2 pnpd[CHK * TB * 6];
    __shared__ float2 comp[CHK * TB];
    __shared__ float vstart[CHK * TB];
    __shared__ float gstate[20], istate[12];

    int tid = threadIdx.x;
    int b = blockIdx.x;
    for (int idx = tid; idx < 384; idx += 512) {
        int d = idx >> 5, e = idx & 31;
        int sl = e * 13 + d;
        preT[sl] = Dg->pre[d][e];
        aT[sl] = Dg->a[d][e];
        bT[sl] = Dg->b[d][e];
        wT[sl] = Dg->w[d][e];
        eT[sl] = Dg->e[d][e];
    }
    if (tid < 12) { cntL[tid] = Dg->cnt[tid]; in0L[tid] = Dg->in0[tid]; id0L[tid] = Dg->id0[tid]; }
    for (int p = tid; p < 4096; p += 512) W2s[p] = d2w[p];
    if (tid < 32) { b2q[tid] = d2b[tid]; iwq[tid] = iw[tid]; ibq[tid] = ib[tid]; }
    {
        const int nw = (int)(sizeof(Tables) / 4);
        const int* src = (const int*)Tg;
        int* dst = (int*)&TL;
        for (int k = tid; k < nw; k += 512) dst[k] = src[k];
    }
    if (tid < 20) gstate[tid] = 0.f;
    if (tid < 12) istate[tid] = 0.f;

    int half = tid >> 8;                       // 0 = solve waves, 1 = dense waves
    int dwid = (tid >> 6) & 3;
    int dlane = tid & 63;
    int dg = dlane >> 3, dl = dlane & 7;
    float w1a[16], w1b[16], b1c[16];
    if (half == 1) {
#pragma unroll
        for (int i = 0; i < 16; ++i) {
            int k = dl * 16 + i;
            w1a[i] = d1w[k]; w1b[i] = d1w[128 + k]; b1c[i] = d1b[k];
        }
    }
    const float2* x2 = (const float2*)x + (size_t)b * NT;
    __syncthreads();

    auto dense_slice = [&](int targ, int ph) {
        int tt = ph * 32 + dwid * 8 + dg;
        float2 xv = x2[targ * TB + tt];
        float* hb = hbuf[dwid][dg];
        float* ibf = ibuf[dwid][dg];
#pragma unroll
        for (int i4 = 0; i4 < 4; ++i4) {
            float4 hq;
            float* hqf = (float*)&hq;
#pragma unroll
            for (int c2 = 0; c2 < 4; ++c2) {
                int i = i4 * 4 + c2;
                float hk = fmaf(xv.y, w1b[i], fmaf(xv.x, w1a[i], b1c[i]));
                hqf[c2] = hk > 0.f ? hk : 0.f;
            }
            *(float4*)&hb[dl * 16 + i4 * 4] = hq;
        }
        float4 acc = make_float4(0.f, 0.f, 0.f, 0.f);
#pragma unroll 4
        for (int k4 = 0; k4 < 32; ++k4) {
            float4 hq = *(const float4*)&hb[k4 * 4];
            int k = k4 * 4;
            const float* hqf = (const float*)&hq;
#pragma unroll
            for (int c2 = 0; c2 < 4; ++c2) {
                float4 w2 = *(const float4*)&W2s[(k + c2) * 32 + dl * 4];
                acc.x = fmaf(hqf[c2], w2.x, acc.x);
                acc.y = fmaf(hqf[c2], w2.y, acc.y);
                acc.z = fmaf(hqf[c2], w2.z, acc.z);
                acc.w = fmaf(hqf[c2], w2.w, acc.w);
            }
        }
        int j0 = dl * 4;
        ibf[j0 + 0] = fmaf(acc.x + b2q[j0 + 0], iwq[j0 + 0], ibq[j0 + 0]);
        ibf[j0 + 1] = fmaf(acc.y + b2q[j0 + 1], iwq[j0 + 1], ibq[j0 + 1]);
        ibf[j0 + 2] = fmaf(acc.z + b2q[j0 + 2], iwq[j0 + 2], ibq[j0 + 2]);
        ibf[j0 + 3] = fmaf(acc.w + b2q[j0 + 3], iwq[j0 + 3], ibq[j0 + 3]);
#pragma unroll
        for (int rep = 0; rep < 2; ++rep) {
            int d = dl + rep * 8;
            if (d < 12) {
                int cnt = cntL[d];
                float wn = in0L[d], wd = id0L[d];
                for (int e = 0; e < cnt; ++e) {
                    int sl = e * 13 + d;
                    float gq = sgm(aT[sl], bT[sl], ibf[preT[sl]]);
                    wn = fmaf(eT[sl], gq, wn);
                    wd = fmaf(wT[sl], gq, wd);
                }
                ring[targ & 1][tt][d] = make_float2(wn, wd);
            }
        }
    };

    // prologue: produce tile 0
    if (half == 1) { dense_slice(0, 0); dense_slice(0, 1); }
    __syncthreads();

    int nchunks = TL.nchunks;
    for (int tile = 0; tile < NTILE; ++tile) {
        int cur = tile & 1;
        // interval 1: solve phase B (inter affine scan) | dense slice 0 of tile+1
        if (half == 0) {
            if (tid < 12) {
                float v = istate[tid];
                float ic = TL.icmt[tid];
#pragma unroll 4
                for (int tt = 0; tt < TB; ++tt) {
                    float2 s = ring[cur][tt][tid];
                    float r = frcp(s.y);
                    float A = ic * r, B = s.x * r;
                    float A2 = A * A, A4 = A2 * A2;
                    float A6 = A4 * A2;
                    float B6 = B * (1.f + A) * (1.f + A2 + A4);
                    viter[tt * 13 + tid] = v;
                    v = fmaf(A6, v, B6);
                }
                istate[tid] = v;
            }
        } else if (tile + 1 < NTILE) {
            dense_slice(tile + 1, 0);
        }
        __syncthreads();
        for (int c = 0; c < nchunks; ++c) {
            int ps = TL.ch_ps[c], pe = TL.ch_pe[c];
            int gs0 = TL.ch_gs[c], ge0 = TL.ch_ge[c];
            int npc = pe - ps;
            // interval: fold | (c==0) dense slice 1
            if (half == 0) {
                for (int w = tid; w < npc * TB; w += 256) {
                    int m = w >> 6, tt = w & (TB - 1);
                    int posi = ps + m;
                    int unit = TL.ord[posi];
                    float pn[6], pd[6];
#pragma unroll
                    for (int u = 0; u < 6; ++u) { pn[u] = TL.cn0[unit]; pd[u] = TL.cd0[unit]; }
                    int ncp = TL.ncp[unit];
                    for (int e = 0; e < ncp; ++e) {
                        int pp = TL.cp_pre[unit][e];
                        float a = TL.cp_a[unit][e], bb = TL.cp_b[unit][e];
                        float w_ = TL.cp_w[unit][e], ev = TL.cp_e[unit][e];
#pragma unroll
                        for (int u = 0; u < 6; ++u) {
                            float gq = sgm(a, bb, vtraj[(pp * TB + tt) * 6 + u]);
                            pn[u] = fmaf(ev, gq, pn[u]);
                            pd[u] = fmaf(w_, gq, pd[u]);
                        }
                    }
                    int nip = TL.nip[unit];
                    for (int e = 0; e < nip; ++e) {
                        int ii = TL.ip_i[unit][e];
                        float2 s = ring[cur][tt][ii];
                        float r = frcp(s.y);
                        float A = TL.icmt[ii] * r, B = s.x * r;
                        float vi = viter[tt * 13 + ii];
                        float a = TL.ip_a[unit][e], bb = TL.ip_b[unit][e];
                        float w_ = TL.ip_w[unit][e], ev = TL.ip_e[unit][e];
#pragma unroll
                        for (int u = 0; u < 6; ++u) {
                            float gq = sgm(a, bb, vi);
                            pn[u] = fmaf(ev, gq, pn[u]);
                            pd[u] = fmaf(w_, gq, pd[u]);
                            vi = fmaf(A, vi, B);
                        }
                    }
                    if (TL.aff[posi]) {
                        float cmt = TL.cmt[unit];
                        float Ac = 1.f, Bc = 0.f;
#pragma unroll
                        for (int u = 0; u < 6; ++u) {
                            float r = frcp(pd[u]);
                            float Au = cmt * r, Bu = pn[u] * r;
                            pnpd[(m * TB + tt) * 6 + u] = make_float2(Au, Bu);
                            Bc = fmaf(Au, Bc, Bu);
                            Ac *= Au;
                        }
                        comp[m * TB + tt] = make_float2(Ac, Bc);
                    } else {
#pragma unroll
                        for (int u = 0; u < 6; ++u)
                            pnpd[(m * TB + tt) * 6 + u] = make_float2(pn[u], pd[u]);
                    }
                }
            } else if (c == 0 && tile + 1 < NTILE) {
                dense_slice(tile + 1, 1);
            }
            __syncthreads();
            // interval: group scans (1 lane per group)
            if (half == 0 && tid < ge0 - gs0) {
                int g = gs0 + tid;
                int gs = TL.grp_start[g], ge = TL.grp_start[g + 1], gsz = ge - gs;
                int m0 = gs - ps;
                if (gsz == 1) {
                    int unit = TL.ord[gs];
                    float v = gstate[gs];
                    if (TL.aff[gs]) {
#pragma unroll 4
                        for (int tt = 0; tt < TB; ++tt) {
                            vstart[m0 * TB + tt] = v;
                            float2 cc = comp[m0 * TB + tt];
                            v = fmaf(cc.x, v, cc.y);
                        }
                    } else {
                        // self-loop: rational form, exp2+rcp only on the chain
                        float ga = TL.gp_a[unit][0], gb = TL.gp_b[unit][0];
                        float gw = TL.gp_w[unit][0], gev = TL.gp_e[unit][0];
                        float cmt = TL.cmt[unit];
                        for (int tt = 0; tt < TB; ++tt) {
#pragma unroll
                            for (int u = 0; u < 6; ++u) {
                                vtraj[(gs * TB + tt) * 6 + u] = v;
                                float2 pp2 = pnpd[(m0 * TB + tt) * 6 + u];
                                float E = ex2(fmaf(ga, v, gb));
                                float P = fmaf(cmt, v, pp2.x);
                                float N = fmaf(P, E, P + gev);
                                float Dd = fmaf(pp2.y, E, pp2.y + gw);
                                v = N * frcp(Dd);
                            }
                        }
                    }
                    gstate[gs] = v;
                } else {
                    float sv[CHK], nv[CHK];
#pragma unroll
                    for (int mm = 0; mm < CHK; ++mm) if (mm < gsz) sv[mm] = gstate[gs + mm];
                    for (int tt = 0; tt < TB; ++tt) {
#pragma unroll
                        for (int u = 0; u < 6; ++u) {
#pragma unroll
                            for (int mm = 0; mm < CHK; ++mm)
                                if (mm < gsz) vtraj[((gs + mm) * TB + tt) * 6 + u] = sv[mm];
#pragma unroll
                            for (int mm = 0; mm < CHK; ++mm) {
                                if (mm < gsz) {
                                    int unit = TL.ord[gs + mm];
                                    float2 pp2 = pnpd[((m0 + mm) * TB + tt) * 6 + u];
                                    float wn = pp2.x, wd = pp2.y;
                                    int ngpu = TL.ngp[unit];
#pragma unroll
                                    for (int e = 0; e < 6; ++e) {
                                        if (e < ngpu) {
                                            float vp = sv[TL.gp_pre[unit][e]];
                                            float gq = sgm(TL.gp_a[unit][e], TL.gp_b[unit][e], vp);
                                            wn = fmaf(TL.gp_e[unit][e], gq, wn);
                                            wd = fmaf(TL.gp_w[unit][e], gq, wd);
                                        }
                                    }
                                    nv[mm] = fmaf(TL.cmt[unit], sv[mm], wn) * frcp(wd);
                                }
                            }
#pragma unroll
                            for (int mm = 0; mm < CHK; ++mm) if (mm < gsz) sv[mm] = nv[mm];
                        }
                    }
#pragma unroll
                    for (int mm = 0; mm < CHK; ++mm) if (mm < gsz) gstate[gs + mm] = sv[mm];
                }
            }
            __syncthreads();
            // interval: expand affine trajectories
            if (half == 0) {
                for (int w = tid; w < npc * TB; w += 256) {
                    int m = w >> 6, tt = w & (TB - 1);
                    int posi = ps + m;
                    if (TL.aff[posi]) {
                        float v = vstart[m * TB + tt];
#pragma unroll
                        for (int u = 0; u < 6; ++u) {
                            vtraj[(posi * TB + tt) * 6 + u] = v;
                            float2 ab = pnpd[(m * TB + tt) * 6 + u];
                            v = fmaf(ab.x, v, ab.y);
                        }
                    }
                }
            }
            __syncthreads();
        }
    }
    if (tid == 0) out[b] = fmaf(gstate[TL.pos[0]], ow[0], ob[0]);
}

extern "C" void kernel_launch(void* const* d_in, const int* in_sizes, int n_in,
                              void* d_out, int out_size, void* d_ws, size_t ws_size,
                              hipStream_t stream) {
    fp x     = (fp)d_in[0];
    fp d1w   = (fp)d_in[1];
    fp d1b   = (fp)d_in[2];
    fp d2w   = (fp)d_in[3];
    fp d2b   = (fp)d_in[4];
    fp iw    = (fp)d_in[5];
    fp ib    = (fp)d_in[6];
    fp ow    = (fp)d_in[7];
    fp ob    = (fp)d_in[8];
    fp gleak = (fp)d_in[9];
    fp vleak = (fp)d_in[10];
    fp cm    = (fp)d_in[11];
    fp wsyn  = (fp)d_in[12];
    fp mu    = (fp)d_in[13];
    fp sigma = (fp)d_in[14];
    fp erev  = (fp)d_in[15];
    fp sw    = (fp)d_in[16];
    fp smu   = (fp)d_in[17];
    fp ssg   = (fp)d_in[18];
    fp serev = (fp)d_in[19];
    const int* spm   = (const int*)d_in[20];
    const int* smask = (const int*)d_in[21];

    char* wsb = (char*)d_ws;
    Tables*   T = (Tables*)wsb;
    DenseTab* D = (DenseTab*)(wsb + WS_DTAB);

    build_tables<<<1, 64, 0, stream>>>(wsyn, mu, sigma, erev, spm,
                                       sw, smu, ssg, serev, smask,
                                       cm, gleak, vleak, T, D);
    fused<<<NB, 512, 0, stream>>>(x, d1w, d1b, d2w, d2b, iw, ib,
                                  D, T, ow, ob, (float*)d_out);
}

// Round 12
// 314.490 us; speedup vs baseline: 1.1450x; 1.1450x over previous
//
#include <hip/hip_runtime.h>

#define NB 256
#define NT 1024
#define NUNF 6
#define TB 64
#define CHK 8
#define L2E 1.44269504088896340736f

typedef const float* fp;

extern "C" __device__ float __ocml_exp2_f32(float);
__device__ __forceinline__ float frcp(float x) { return __builtin_amdgcn_rcpf(x); }
__device__ __forceinline__ float ex2(float x) { return __ocml_exp2_f32(x); }
__device__ __forceinline__ float sgm(float a, float b, float v) { return frcp(1.f + ex2(fmaf(a, v, b))); }

struct Tables {
    int ngroups, npos, nchunks, pad0;
    int grp_start[21];
    int ord[20];
    int pos[20];
    int aff[20];
    int need_traj[20];
    int ch_ps[20], ch_pe[20], ch_gs[20], ch_ge[20];
    int ncp[20], nip[20], ngp[20];
    float cmt[20], cn0[20], cd0[20];
    float icmt[12];
    int   cp_pre[20][8];
    float cp_a[20][8], cp_b[20][8], cp_w[20][8], cp_e[20][8];
    int   ip_i[20][12];
    float ip_a[20][12], ip_b[20][12], ip_w[20][12], ip_e[20][12];
    int   gp_pre[20][6];
    float gp_a[20][6], gp_b[20][6], gp_w[20][6], gp_e[20][6];
};

struct DenseTab {
    int cnt[12];
    float in0[12], id0[12];
    int   pre[12][32];
    float a[12][32], b[12][32], w[12][32], e[12][32];
};

#define WS_DTAB   16384
#define WS_VSTATE 24576
#define WS_SENSI  65536

// ---------------- K0: wiring analysis, lane-parallel in LDS ----------------
__global__ void build_tables(fp wsyn, fp mu, fp sigma, fp erev, const int* spm,
                             fp sw, fp smu, fp ssg, fp serev, const int* smask,
                             fp cm, fp gleak, fp vleak, Tables* T, DenseTab* D) {
    __shared__ int   spmL[1024], smkL[1024];
    __shared__ float wL[1024], muL[1024], sgL[1024], evL[1024];
    __shared__ float swL[1024], smuL[1024], ssgL[1024], sevL[1024];
    __shared__ float cmL[32], glL[32], vlL[32];
    __shared__ int premaskL[20], ancL[20], rootL[20], depUL[20], keyL[20], posL[20], ordL[20];
    __shared__ int ngpL[20];
    __shared__ int neededS;
    int tid = threadIdx.x;
    for (int k = tid; k < 1024; k += 64) {
        spmL[k] = spm[k]; wL[k] = wsyn[k]; muL[k] = mu[k]; sgL[k] = sigma[k]; evL[k] = erev[k];
        smkL[k] = smask[k]; swL[k] = sw[k]; smuL[k] = smu[k]; ssgL[k] = ssg[k]; sevL[k] = serev[k];
    }
    if (tid < 32) { cmL[tid] = cm[tid]; glL[tid] = gleak[tid]; vlL[tid] = vleak[tid]; }
    __syncthreads();
    if (tid < 20) {
        int pm = 0;
        for (int i = 0; i < 20; ++i) if (spmL[i * 32 + tid]) pm |= 1 << i;
        premaskL[tid] = pm;
        ancL[tid] = pm;
    }
    __syncthreads();
    for (int it = 0; it < 20; ++it) {
        int a = 0;
        if (tid < 20) {
            a = ancL[tid];
            int pm = premaskL[tid];
            for (int i = 0; i < 20; ++i) if ((pm >> i) & 1) a |= ancL[i];
        }
        __syncthreads();
        if (tid < 20) ancL[tid] = a;
        __syncthreads();
    }
    if (tid == 0) neededS = ancL[0] | 1;
    __syncthreads();
    int needed = neededS;
    if (tid < 20) {
        int r = tid;
        if ((needed >> tid) & 1) {
            int aj = ancL[tid];
            for (int i = 0; i < 20; ++i)
                if (i < r && ((needed >> i) & 1) && ((aj >> i) & 1) && ((ancL[i] >> tid) & 1)) r = i;
        }
        rootL[tid] = r;
        depUL[tid] = 0;
    }
    __syncthreads();
    for (int it = 0; it < 21; ++it) {
        int d = 0;
        if (tid < 20 && ((needed >> tid) & 1)) {
            int pm = premaskL[tid], myr = rootL[tid];
            for (int i = 0; i < 20; ++i)
                if (((pm >> i) & 1) && rootL[i] != myr) d = max(d, depUL[i] + 1);
        }
        __syncthreads();
        if (tid < 20 && d > depUL[tid]) depUL[tid] = d;
        __syncthreads();
    }
    if (tid < 20) {
        int key = 0x7FFFFFFF;
        if ((needed >> tid) & 1) {
            int myr = rootL[tid], dg = 0;
            for (int i = 0; i < 20; ++i)
                if (((needed >> i) & 1) && rootL[i] == myr) dg = max(dg, depUL[i]);
            key = dg * 32 + myr;
        }
        keyL[tid] = key;
    }
    __syncthreads();
    if (tid < 20) {
        int mykey = keyL[tid];
        int p = 0;
        for (int k = 0; k < 20; ++k)
            if (keyL[k] < mykey || (keyL[k] == mykey && k < tid)) ++p;
        posL[tid] = p;
        if (p < 20) ordL[p] = tid;
    }
    __syncthreads();
    if (tid < 20) {
        int j = tid, cc = 0, ci = 0, cg = 0;
        T->cmt[j] = cmL[j] * (float)NUNF;
        T->cn0[j] = glL[j] * vlL[j];
        T->cd0[j] = cmL[j] * (float)NUNF + glL[j] + 1e-8f;
        if ((needed >> j) & 1) {
            int myr = rootL[j];
            int mystart = posL[myr];
            for (int i = 0; i < 32; ++i) {
                int p = i * 32 + j;
                if (!spmL[p]) continue;
                float sg = sgL[p];
                float a = -sg * L2E, b = sg * muL[p] * L2E;
                float w = wL[p], e = w * evL[p];
                if (i >= 20) {
                    T->ip_i[j][ci] = i - 20;
                    T->ip_a[j][ci] = a; T->ip_b[j][ci] = b; T->ip_w[j][ci] = w; T->ip_e[j][ci] = e;
                    ++ci;
                } else if (rootL[i] == myr) {
                    T->gp_pre[j][cg] = posL[i] - mystart;
                    T->gp_a[j][cg] = a; T->gp_b[j][cg] = b; T->gp_w[j][cg] = w; T->gp_e[j][cg] = e;
                    ++cg;
                } else {
                    T->cp_pre[j][cc] = posL[i];
                    T->cp_a[j][cc] = a; T->cp_b[j][cc] = b; T->cp_w[j][cc] = w; T->cp_e[j][cc] = e;
                    ++cc;
                }
            }
        }
        T->ncp[j] = cc; T->nip[j] = ci; T->ngp[j] = cg;
        ngpL[j] = cg;
    }
    if (tid < 12) {
        T->icmt[tid] = cmL[20 + tid] * (float)NUNF;
        int unit = 20 + tid, cnt = 0;
        for (int s = 0; s < 32; ++s) {
            int p = s * 32 + unit;
            if (!smkL[p]) continue;
            float sg = ssgL[p];
            D->pre[tid][cnt] = s;
            D->a[tid][cnt] = -sg * L2E;
            D->b[tid][cnt] = sg * smuL[p] * L2E;
            D->w[tid][cnt] = swL[p];
            D->e[tid][cnt] = swL[p] * sevL[p];
            ++cnt;
        }
        for (int c = cnt; c < 32; ++c) {
            D->pre[tid][c] = 0; D->a[tid][c] = 0.f; D->b[tid][c] = 0.f;
            D->w[tid][c] = 0.f; D->e[tid][c] = 0.f;
        }
        D->cnt[tid] = cnt;
        D->in0[tid] = glL[unit] * vlL[unit];
        D->id0[tid] = cmL[unit] * (float)NUNF + glL[unit] + 1e-8f;
    }
    __syncthreads();
    if (tid == 0) {
        int npos = __popc(needed & 0xFFFFF);
        T->npos = npos;
        int ng = 0, prevkey = -1;
        for (int p = 0; p < npos; ++p) {
            int u = ordL[p];
            if (keyL[u] != prevkey) { T->grp_start[ng] = p; ++ng; prevkey = keyL[u]; }
        }
        T->ngroups = ng;
        for (int g = ng; g <= 20; ++g) T->grp_start[g] = npos;
        for (int p = 0; p < 20; ++p) T->ord[p] = (p < npos) ? ordL[p] : 0;
        for (int j = 0; j < 20; ++j) T->pos[j] = posL[j];
        for (int g = 0; g < ng; ++g) {
            int gs = T->grp_start[g], ge = T->grp_start[g + 1], gsz = ge - gs;
            for (int p = gs; p < ge; ++p)
                T->aff[p] = (gsz == 1 && ngpL[ordL[p]] == 0) ? 1 : 0;
        }
        for (int p = npos; p < 20; ++p) T->aff[p] = 0;
        // need_traj[pos(i)] = 1 iff some OTHER needed unit consumes i's trajectory
        for (int p = 0; p < 20; ++p) T->need_traj[p] = 0;
        for (int i = 0; i < 20; ++i) {
            if (!((needed >> i) & 1)) continue;
            for (int j = 0; j < 20; ++j)
                if (j != i && ((needed >> j) & 1) && spmL[i * 32 + j]) { T->need_traj[posL[i]] = 1; break; }
        }
        int nchunks = 0, g = 0;
        while (g < ng) {
            int lvl = keyL[ordL[T->grp_start[g]]] / 32;
            int ge = g;
            while (ge < ng && keyL[ordL[T->grp_start[ge]]] / 32 == lvl) ++ge;
            int cs = g;
            while (cs < ge) {
                int ce = cs, acc = 0;
                while (ce < ge) {
                    int gsz = T->grp_start[ce + 1] - T->grp_start[ce];
                    if (acc + gsz > CHK && ce > cs) break;
                    acc += gsz; ++ce;
                    if (acc >= CHK) break;
                }
                T->ch_gs[nchunks] = cs; T->ch_ge[nchunks] = ce;
                T->ch_ps[nchunks] = T->grp_start[cs]; T->ch_pe[nchunks] = T->grp_start[ce];
                ++nchunks;
                cs = ce;
            }
            g = ge;
        }
        T->nchunks = nchunks;
    }
}

// ---------------- K1: dense stack + sensory gates. 8 lanes per (b,t). (R10 version) ----------------
__global__ __launch_bounds__(256) void dense_sens(
    fp x, fp d1w, fp d1b, fp d2w, fp d2b, fp iw, fp ib,
    const DenseTab* __restrict__ Dg, float2* sensI, int t0, int CT) {
    __shared__ float W2s[4096];
    __shared__ float b2q[32], iwq[32], ibq[32];
    __shared__ int   preT[32 * 13];
    __shared__ float aT[32 * 13], bT[32 * 13], wT[32 * 13], eT[32 * 13];
    __shared__ int   cntL[12];
    __shared__ float in0L[12], id0L[12];
    __shared__ float hbuf[4][8][132];
    __shared__ float ibuf[4][8][33];
    int tid = threadIdx.x;
    for (int idx = tid; idx < 384; idx += 256) {
        int d = idx >> 5, e = idx & 31;
        int sl = e * 13 + d;
        preT[sl] = Dg->pre[d][e];
        aT[sl] = Dg->a[d][e];
        bT[sl] = Dg->b[d][e];
        wT[sl] = Dg->w[d][e];
        eT[sl] = Dg->e[d][e];
    }
    if (tid < 12) { cntL[tid] = Dg->cnt[tid]; in0L[tid] = Dg->in0[tid]; id0L[tid] = Dg->id0[tid]; }
    for (int p = tid; p < 4096; p += 256) W2s[p] = d2w[p];
    if (tid < 32) { b2q[tid] = d2b[tid]; iwq[tid] = iw[tid]; ibq[tid] = ib[tid]; }
    __syncthreads();
    int wid = tid >> 6, lane = tid & 63;
    int g = lane >> 3, l = lane & 7;
    float w1a[16], w1b[16], b1c[16];
#pragma unroll
    for (int i = 0; i < 16; ++i) {
        int k = l * 16 + i;
        w1a[i] = d1w[k]; w1b[i] = d1w[128 + k]; b1c[i] = d1b[k];
    }
    float* hb = hbuf[wid][g];
    float* ibf = ibuf[wid][g];
    const float2* x2 = (const float2*)x;
    int gwid = blockIdx.x * 4 + wid;
    int nw = gridDim.x * 4;
    int niters = (NB * CT) >> 3;
    for (int it = gwid; it < niters; it += nw) {
        int cg = it * 8 + g;
        int lt = cg >> 8, b = cg & 255;
        float2 xv = x2[b * NT + (t0 + lt)];
#pragma unroll
        for (int i4 = 0; i4 < 4; ++i4) {
            float4 hq;
            float* hqf = (float*)&hq;
#pragma unroll
            for (int c = 0; c < 4; ++c) {
                int i = i4 * 4 + c;
                float hk = fmaf(xv.y, w1b[i], fmaf(xv.x, w1a[i], b1c[i]));
                hqf[c] = hk > 0.f ? hk : 0.f;
            }
            *(float4*)&hb[l * 16 + i4 * 4] = hq;
        }
        float4 acc = make_float4(0.f, 0.f, 0.f, 0.f);
#pragma unroll 8
        for (int k = 0; k < 128; ++k) {
            float hk = hb[k];
            float4 w2 = *(const float4*)&W2s[k * 32 + l * 4];
            acc.x = fmaf(hk, w2.x, acc.x);
            acc.y = fmaf(hk, w2.y, acc.y);
            acc.z = fmaf(hk, w2.z, acc.z);
            acc.w = fmaf(hk, w2.w, acc.w);
        }
        int j0 = l * 4;
        ibf[j0 + 0] = fmaf(acc.x + b2q[j0 + 0], iwq[j0 + 0], ibq[j0 + 0]);
        ibf[j0 + 1] = fmaf(acc.y + b2q[j0 + 1], iwq[j0 + 1], ibq[j0 + 1]);
        ibf[j0 + 2] = fmaf(acc.z + b2q[j0 + 2], iwq[j0 + 2], ibq[j0 + 2]);
        ibf[j0 + 3] = fmaf(acc.w + b2q[j0 + 3], iwq[j0 + 3], ibq[j0 + 3]);
#pragma unroll
        for (int rep = 0; rep < 2; ++rep) {
            int d = l + rep * 8;
            if (d < 12) {
                int cnt = cntL[d];
                float wn = in0L[d], wd = id0L[d];
                for (int e = 0; e < cnt; ++e) {
                    int sl = e * 13 + d;
                    float gq = sgm(aT[sl], bT[sl], ibf[preT[sl]]);
                    wn = fmaf(eT[sl], gq, wn);
                    wd = fmaf(wT[sl], gq, wd);
                }
                sensI[(size_t)(b * CT + lt) * 12 + d] = make_float2(wn, wd);
            }
        }
    }
}

// ---------------- K2: per-batch level-parallel solver (512 threads) ----------------
__global__ __launch_bounds__(512) void solve(const float2* __restrict__ sensI,
                                             const Tables* __restrict__ Tg,
                                             fp ow, fp ob, float* vstate,
                                             int t0, int CT, float* out) {
    __shared__ Tables TL;
    __shared__ float2 iAB[TB * 12];
    __shared__ float2 icomp[TB * 12];
    __shared__ float viter[TB * 13];
    __shared__ float vtraj[20 * TB * 7];        // stride 7: gcd(7,32)=1
    __shared__ float2 pnpd[CHK * TB * 7];
    __shared__ float2 comp[CHK * TB];
    __shared__ float vstart[CHK * TB];
    __shared__ float gstate[20], istate[12];
    int tid = threadIdx.x;
    int b = blockIdx.x;
    {
        const int nw = (int)(sizeof(Tables) / 4);
        const int* src = (const int*)Tg;
        int* dst = (int*)&TL;
        for (int k = tid; k < nw; k += 512) dst[k] = src[k];
    }
    __syncthreads();
    if (tid < 20 && tid < TL.npos)
        gstate[tid] = (t0 == 0) ? 0.f : vstate[b * 32 + TL.ord[tid]];
    if (tid < 12)
        istate[tid] = (t0 == 0) ? 0.f : vstate[b * 32 + 20 + tid];
    __syncthreads();
    int ntiles = CT / TB;
    bool lastChunk = (t0 + CT == NT);
    for (int tile = 0; tile < ntiles; ++tile) {
        int tbase = tile * TB;
        for (int w = tid; w < TB * 16; w += 512) {
            int tt = w >> 4, ii = w & 15;
            if (ii < 12) {
                float2 s = sensI[(size_t)(b * CT + tbase + tt) * 12 + ii];
                float r = frcp(s.y);
                float A = TL.icmt[ii] * r, B = s.x * r;
                iAB[tt * 12 + ii] = make_float2(A, B);
                float A2 = A * A, A4 = A2 * A2;
                float A6 = A4 * A2;
                float B6 = B * (1.f + A) * (1.f + A2 + A4);
                icomp[tt * 12 + ii] = make_float2(A6, B6);
            }
        }
        __syncthreads();
        if (tid < 12) {
            float v = istate[tid];
#pragma unroll 4
            for (int tt = 0; tt < TB; ++tt) {
                viter[tt * 13 + tid] = v;
                float2 cc = icomp[tt * 12 + tid];
                v = fmaf(cc.x, v, cc.y);
            }
            istate[tid] = v;
        }
        __syncthreads();
        int nchunks = TL.nchunks;
        for (int c = 0; c < nchunks; ++c) {
            int ps = TL.ch_ps[c], pe = TL.ch_pe[c];
            int gs0 = TL.ch_gs[c], ge0 = TL.ch_ge[c];
            int npc = pe - ps;
            for (int w = tid; w < npc * TB; w += 512) {
                int m = w >> 6, tt = w & (TB - 1);
                int posi = ps + m;
                int unit = TL.ord[posi];
                float pn[6], pd[6];
#pragma unroll
                for (int u = 0; u < 6; ++u) { pn[u] = TL.cn0[unit]; pd[u] = TL.cd0[unit]; }
                int ncp = TL.ncp[unit];
                for (int e = 0; e < ncp; ++e) {
                    int pp = TL.cp_pre[unit][e];
                    float a = TL.cp_a[unit][e], bb = TL.cp_b[unit][e];
                    float w_ = TL.cp_w[unit][e], ev = TL.cp_e[unit][e];
#pragma unroll
                    for (int u = 0; u < 6; ++u) {
                        float gq = sgm(a, bb, vtraj[(pp * TB + tt) * 7 + u]);
                        pn[u] = fmaf(ev, gq, pn[u]);
                        pd[u] = fmaf(w_, gq, pd[u]);
                    }
                }
                int nip = TL.nip[unit];
                for (int e = 0; e < nip; ++e) {
                    int ii = TL.ip_i[unit][e];
                    float2 ab = iAB[tt * 12 + ii];
                    float vi = viter[tt * 13 + ii];
                    float a = TL.ip_a[unit][e], bb = TL.ip_b[unit][e];
                    float w_ = TL.ip_w[unit][e], ev = TL.ip_e[unit][e];
#pragma unroll
                    for (int u = 0; u < 6; ++u) {
                        float gq = sgm(a, bb, vi);
                        pn[u] = fmaf(ev, gq, pn[u]);
                        pd[u] = fmaf(w_, gq, pd[u]);
                        vi = fmaf(ab.x, vi, ab.y);
                    }
                }
                if (TL.aff[posi]) {
                    float cmt = TL.cmt[unit];
                    float Ac = 1.f, Bc = 0.f;
#pragma unroll
                    for (int u = 0; u < 6; ++u) {
                        float r = frcp(pd[u]);
                        float Au = cmt * r, Bu = pn[u] * r;
                        pnpd[(m * TB + tt) * 7 + u] = make_float2(Au, Bu);
                        Bc = fmaf(Au, Bc, Bu);
                        Ac *= Au;
                    }
                    comp[m * TB + tt] = make_float2(Ac, Bc);
                } else {
#pragma unroll
                    for (int u = 0; u < 6; ++u)
                        pnpd[(m * TB + tt) * 7 + u] = make_float2(pn[u], pd[u]);
                }
            }
            __syncthreads();
            if (tid < ge0 - gs0) {
                int g = gs0 + tid;
                int gs = TL.grp_start[g], ge = TL.grp_start[g + 1], gsz = ge - gs;
                int m0 = gs - ps;
                if (gsz == 1) {
                    int unit = TL.ord[gs];
                    float v = gstate[gs];
                    if (TL.aff[gs]) {
#pragma unroll 4
                        for (int tt = 0; tt < TB; ++tt) {
                            vstart[m0 * TB + tt] = v;
                            float2 cc = comp[m0 * TB + tt];
                            v = fmaf(cc.x, v, cc.y);
                        }
                    } else {
                        // self-loop singleton: rational form, exp2+rcp only on chain
                        float ga = TL.gp_a[unit][0], gb = TL.gp_b[unit][0];
                        float gw = TL.gp_w[unit][0], gev = TL.gp_e[unit][0];
                        float cmt = TL.cmt[unit];
                        int ntj = TL.need_traj[gs];
                        for (int tt = 0; tt < TB; ++tt) {
#pragma unroll
                            for (int u = 0; u < 6; ++u) {
                                if (ntj) vtraj[(gs * TB + tt) * 7 + u] = v;
                                float2 pp2 = pnpd[(m0 * TB + tt) * 7 + u];
                                float E = ex2(fmaf(ga, v, gb));
                                float P = fmaf(cmt, v, pp2.x);
                                float N = fmaf(P, E, P + gev);
                                float Dd = fmaf(pp2.y, E, pp2.y + gw);
                                v = N * frcp(Dd);
                            }
                        }
                    }
                    gstate[gs] = v;
                } else {
                    float sv[CHK], nv[CHK];
#pragma unroll
                    for (int mm = 0; mm < CHK; ++mm) if (mm < gsz) sv[mm] = gstate[gs + mm];
                    for (int tt = 0; tt < TB; ++tt) {
#pragma unroll
                        for (int u = 0; u < 6; ++u) {
#pragma unroll
                            for (int mm = 0; mm < CHK; ++mm)
                                if (mm < gsz) vtraj[((gs + mm) * TB + tt) * 7 + u] = sv[mm];
#pragma unroll
                            for (int mm = 0; mm < CHK; ++mm) {
                                if (mm < gsz) {
                                    int unit = TL.ord[gs + mm];
                                    float2 pp2 = pnpd[((m0 + mm) * TB + tt) * 7 + u];
                                    float wn = pp2.x, wd = pp2.y;
                                    int ngpu = TL.ngp[unit];
#pragma unroll
                                    for (int e = 0; e < 6; ++e) {
                                        if (e < ngpu) {
                                            float vp = sv[TL.gp_pre[unit][e]];
                                            float gq = sgm(TL.gp_a[unit][e], TL.gp_b[unit][e], vp);
                                            wn = fmaf(TL.gp_e[unit][e], gq, wn);
                                            wd = fmaf(TL.gp_w[unit][e], gq, wd);
                                        }
                                    }
                                    nv[mm] = fmaf(TL.cmt[unit], sv[mm], wn) * frcp(wd);
                                }
                            }
#pragma unroll
                            for (int mm = 0; mm < CHK; ++mm) if (mm < gsz) sv[mm] = nv[mm];
                        }
                    }
#pragma unroll
                    for (int mm = 0; mm < CHK; ++mm) if (mm < gsz) gstate[gs + mm] = sv[mm];
                }
            }
            __syncthreads();
            for (int w = tid; w < npc * TB; w += 512) {
                int m = w >> 6, tt = w & (TB - 1);
                int posi = ps + m;
                if (TL.aff[posi] && TL.need_traj[posi]) {
                    float v = vstart[m * TB + tt];
#pragma unroll
                    for (int u = 0; u < 6; ++u) {
                        vtraj[(posi * TB + tt) * 7 + u] = v;
                        float2 ab = pnpd[(m * TB + tt) * 7 + u];
                        v = fmaf(ab.x, v, ab.y);
                    }
                }
            }
            __syncthreads();
        }
    }
    if (tid < 20 && tid < TL.npos) vstate[b * 32 + TL.ord[tid]] = gstate[tid];
    if (tid < 12) vstate[b * 32 + 20 + tid] = istate[tid];
    if (lastChunk) {
        __syncthreads();
        if (tid == 0) out[b] = fmaf(gstate[TL.pos[0]], ow[0], ob[0]);
    }
}

extern "C" void kernel_launch(void* const* d_in, const int* in_sizes, int n_in,
                              void* d_out, int out_size, void* d_ws, size_t ws_size,
                              hipStream_t stream) {
    fp x     = (fp)d_in[0];
    fp d1w   = (fp)d_in[1];
    fp d1b   = (fp)d_in[2];
    fp d2w   = (fp)d_in[3];
    fp d2b   = (fp)d_in[4];
    fp iw    = (fp)d_in[5];
    fp ib    = (fp)d_in[6];
    fp ow    = (fp)d_in[7];
    fp ob    = (fp)d_in[8];
    fp gleak = (fp)d_in[9];
    fp vleak = (fp)d_in[10];
    fp cm    = (fp)d_in[11];
    fp wsyn  = (fp)d_in[12];
    fp mu    = (fp)d_in[13];
    fp sigma = (fp)d_in[14];
    fp erev  = (fp)d_in[15];
    fp sw    = (fp)d_in[16];
    fp smu   = (fp)d_in[17];
    fp ssg   = (fp)d_in[18];
    fp serev = (fp)d_in[19];
    const int* spm   = (const int*)d_in[20];
    const int* smask = (const int*)d_in[21];

    char* wsb = (char*)d_ws;
    Tables*   T = (Tables*)wsb;
    DenseTab* D = (DenseTab*)(wsb + WS_DTAB);
    float* vstate = (float*)(wsb + WS_VSTATE);
    float2* sensI = (float2*)(wsb + WS_SENSI);

    size_t per_t = (size_t)NB * 12 * sizeof(float2);     // 24576 B
    int CT = TB;
    if (ws_size > WS_SENSI) {
        size_t m = (ws_size - WS_SENSI) / per_t;
        int ct = TB;
        while (ct < NT && (size_t)(ct * 2) <= m) ct *= 2;
        CT = ct;
    }

    build_tables<<<1, 64, 0, stream>>>(wsyn, mu, sigma, erev, spm,
                                       sw, smu, ssg, serev, smask,
                                       cm, gleak, vleak, T, D);

    int nch = NT / CT;
    for (int c = 0; c < nch; ++c) {
        int t0 = c * CT;
        dense_sens<<<768, 256, 0, stream>>>(x, d1w, d1b, d2w, d2b, iw, ib,
                                            D, sensI, t0, CT);
        solve<<<NB, 512, 0, stream>>>(sensI, T, ow, ob, vstate, t0, CT, (float*)d_out);
    }
}